// Round 2
// baseline (1176.491 us; speedup 1.0000x reference)
//
#include <hip/hip_runtime.h>

// ---- problem constants ----
#define T_LEN   240
#define B_SZ    8
#define NFILT   2560
#define KD      9216          // 96*96
#define M_DIM   1920          // B*T
#define N_DIM   5120          // 2*NF (sin | cos)
#define PAD_L   8
#define KSPLIT  2
#define KHALF   4608

typedef unsigned short u16;
typedef __attribute__((ext_vector_type(8)))  __bf16 bf16x8;
typedef __attribute__((ext_vector_type(16))) float  f32x16;

// ---------- fp32 -> (hi,lo) bf16 split, RNE both halves ----------
__device__ __forceinline__ u16 f2bf_rne(float f) {
    unsigned u = __float_as_uint(f);
    u += 0x7FFFu + ((u >> 16) & 1u);
    return (u16)(u >> 16);
}

__device__ __forceinline__ void split4(const float* __restrict__ src,
                                       u16* __restrict__ hi, u16* __restrict__ lo, int i) {
    const float4 v = ((const float4*)src)[i];
    float vv[4] = {v.x, v.y, v.z, v.w};
    u16 hh[4], ll[4];
#pragma unroll
    for (int j = 0; j < 4; ++j) {
        unsigned u = __float_as_uint(vv[j]);
        unsigned r = u + 0x7FFFu + ((u >> 16) & 1u);
        u16 hb = (u16)(r >> 16);
        float hf = __uint_as_float((unsigned)hb << 16);
        hh[j] = hb;
        ll[j] = f2bf_rne(vv[j] - hf);   // residual exact in fp32, then RNE
    }
    ushort4 h, l;
    h.x = hh[0]; h.y = hh[1]; h.z = hh[2]; h.w = hh[3];
    l.x = ll[0]; l.y = ll[1]; l.z = ll[2]; l.w = ll[3];
    ((ushort4*)hi)[i] = h;
    ((ushort4*)lo)[i] = l;
}

// one fused launch: x | w_sin | w_cos regions
#define NX4  (17694720 / 4)
#define NW4  (23592960 / 4)
__global__ void split_all_kernel(const float* __restrict__ x,
                                 const float* __restrict__ wss,
                                 const float* __restrict__ wsc,
                                 u16* __restrict__ xh, u16* __restrict__ xl,
                                 u16* __restrict__ wh, u16* __restrict__ wl) {
    int i = blockIdx.x * 256 + threadIdx.x;
    if (i < NX4) {
        split4(x, xh, xl, i);
    } else if (i < NX4 + NW4) {
        split4(wss, wh, wl, i - NX4);
    } else if (i < NX4 + 2 * NW4) {
        int j = i - NX4 - NW4;
        split4(wsc, wh + (size_t)NFILT * KD / 4 * 4, wl + (size_t)NFILT * KD, j);
    }
}

// ---------- async global->LDS, 16B per lane ----------
__device__ __forceinline__ void glds16(const u16* gp, __bf16* lp) {
    __builtin_amdgcn_global_load_lds(
        (const __attribute__((address_space(1))) void*)gp,
        (__attribute__((address_space(3))) void*)lp, 16, 0, 0);
}

// ---------- bf16x3 split GEMM: C = Ah*Bh + Ah*Bl + Al*Bh  (32x32x16 MFMA, split-K=2) ----------
// A = x splits (M=1920 x K=9216), B^T = w splits (N=5120 x K=9216), C = g (M x N) fp32 (atomicAdd)
__global__ __launch_bounds__(256, 4) void gemm_split_kernel(
    const u16* __restrict__ xh, const u16* __restrict__ xl,
    const u16* __restrict__ wh, const u16* __restrict__ wl,
    float* __restrict__ g) {

    __shared__ __align__(16) __bf16 sAh[128 * 32];
    __shared__ __align__(16) __bf16 sAl[128 * 32];
    __shared__ __align__(16) __bf16 sBh[128 * 32];
    __shared__ __align__(16) __bf16 sBl[128 * 32];

    const int tid = threadIdx.x;
    const int l   = tid & 63;
    const int w   = tid >> 6;
    const int tb  = blockIdx.x % 600;
    const int kbase = (blockIdx.x / 600) * KHALF;   // split-K slice
    const int m0  = (tb / 40) * 128;                // 15 m-tiles
    const int n0  = (tb % 40) * 128;                // 40 n-tiles

    // staging: tile[128][32] bf16 row-major; lane l writes LDS base + l*16
    const int srow = w * 16 + (l >> 2);
    const int skc  = (l & 3) * 8;
    const size_t aOff0 = (size_t)(m0 + srow) * KD + skc + kbase;
    const size_t aOff1 = aOff0 + (size_t)64 * KD;
    const size_t bOff0 = (size_t)(n0 + srow) * KD + skc + kbase;
    const size_t bOff1 = bOff0 + (size_t)64 * KD;
    const int ldsOff0 = srow * 32 + skc;
    const int ldsOff1 = ldsOff0 + 64 * 32;

    // compute mapping: wave (wr,wc) owns 64x64 = 2x2 tiles of 32x32x16
    const int wr = (w >> 1) * 64;
    const int wc = (w & 1) * 64;
    const int rowin = l & 31;          // A/B fragment: m(or n) = lane&31
    const int kq    = (l >> 5) * 8;    // k-quad base within 16-wide substep

    f32x16 acc[2][2];
#pragma unroll
    for (int i = 0; i < 2; ++i)
#pragma unroll
        for (int j = 0; j < 2; ++j)
#pragma unroll
            for (int r = 0; r < 16; ++r)
                acc[i][j][r] = 0.f;

    for (int kt = 0; kt < KHALF; kt += 32) {
        glds16(xh + aOff0 + kt, &sAh[ldsOff0]);
        glds16(xh + aOff1 + kt, &sAh[ldsOff1]);
        glds16(xl + aOff0 + kt, &sAl[ldsOff0]);
        glds16(xl + aOff1 + kt, &sAl[ldsOff1]);
        glds16(wh + bOff0 + kt, &sBh[ldsOff0]);
        glds16(wh + bOff1 + kt, &sBh[ldsOff1]);
        glds16(wl + bOff0 + kt, &sBl[ldsOff0]);
        glds16(wl + bOff1 + kt, &sBl[ldsOff1]);
        __syncthreads();

#pragma unroll
        for (int ks = 0; ks < 32; ks += 16) {
            const int fo = ks + kq;
            bf16x8 ah[2], al[2], bh[2], bl[2];
#pragma unroll
            for (int t = 0; t < 2; ++t) {
                ah[t] = *(const bf16x8*)&sAh[(wr + t * 32 + rowin) * 32 + fo];
                al[t] = *(const bf16x8*)&sAl[(wr + t * 32 + rowin) * 32 + fo];
                bh[t] = *(const bf16x8*)&sBh[(wc + t * 32 + rowin) * 32 + fo];
                bl[t] = *(const bf16x8*)&sBl[(wc + t * 32 + rowin) * 32 + fo];
            }
#pragma unroll
            for (int tr = 0; tr < 2; ++tr)
#pragma unroll
                for (int tc = 0; tc < 2; ++tc) {
                    acc[tr][tc] = __builtin_amdgcn_mfma_f32_32x32x16_bf16(ah[tr], bh[tc], acc[tr][tc], 0, 0, 0);
                    acc[tr][tc] = __builtin_amdgcn_mfma_f32_32x32x16_bf16(ah[tr], bl[tc], acc[tr][tc], 0, 0, 0);
                    acc[tr][tc] = __builtin_amdgcn_mfma_f32_32x32x16_bf16(al[tr], bh[tc], acc[tr][tc], 0, 0, 0);
                }
        }
        __syncthreads();
    }

    // epilogue: 32x32 C/D layout col = l&31, row = (r&3) + 8*(r>>2) + 4*(l>>5)  (m74/m101)
    const int cbase = (l >> 5) * 4;
    const int ccol  = l & 31;
#pragma unroll
    for (int tr = 0; tr < 2; ++tr)
#pragma unroll
        for (int tc = 0; tc < 2; ++tc) {
            const int col = n0 + wc + tc * 32 + ccol;
#pragma unroll
            for (int r = 0; r < 16; ++r) {
                const int row = m0 + wr + tr * 32 + (r & 3) + 8 * (r >> 2) + cbase;
                atomicAdd(g + (size_t)row * N_DIM + col, acc[tr][tc][r]);
            }
        }
}

// ---------- depthwise temporal conv (cross-corr, pad 8/7) + energy ----------
__global__ void conv_energy_kernel(const float* __restrict__ g,
                                   const float* __restrict__ wts,
                                   const float* __restrict__ wtc,
                                   float* __restrict__ out) {
    const int idx = blockIdx.x * 256 + threadIdx.x;
    const int f  = idx % NFILT;
    const int bt = idx / NFILT;
    const int t  = bt % T_LEN;
    const int b  = bt / T_LEN;
    const float* grow = g + (size_t)b * T_LEN * N_DIM + f;
    const float* pwc = wtc + f * 16;
    const float* pws = wts + f * 16;
    float s = 0.f, c = 0.f;
#pragma unroll
    for (int j = 0; j < 16; ++j) {
        const int tt = t + j - PAD_L;
        if (tt >= 0 && tt < T_LEN) {   // uniform across the block (f varies, t fixed)
            const float gs = grow[(size_t)tt * N_DIM];
            const float gc = grow[(size_t)tt * N_DIM + NFILT];
            const float a = pwc[j], bb = pws[j];
            s += gs * a + gc * bb;
            c += gc * a - gs * bb;
        }
    }
    const float r = sqrtf(s * s + c * c);
    out[idx] = logf(r + 1e-5f);
}

extern "C" void kernel_launch(void* const* d_in, const int* in_sizes, int n_in,
                              void* d_out, int out_size, void* d_ws, size_t ws_size,
                              hipStream_t stream) {
    const float* x   = (const float*)d_in[0];  // (8,240,96,96)
    const float* wss = (const float*)d_in[1];  // (2560,96,96)
    const float* wsc = (const float*)d_in[2];  // (2560,96,96)
    const float* wts = (const float*)d_in[3];  // (2560,16)
    const float* wtc = (const float*)d_in[4];  // (2560,16)
    float* out = (float*)d_out;

    // workspace layout (bytes):
    //   xh: 35,389,440 | xl: 35,389,440 | wh: 94,371,840 | wl: 94,371,840 | g: 39,321,600
    char* ws = (char*)d_ws;
    u16*   xh  = (u16*)(ws);
    u16*   xl  = (u16*)(ws + 35389440);
    u16*   whi = (u16*)(ws + 70778880);
    u16*   wlo = (u16*)(ws + 165150720);
    float* g   = (float*)(ws + 259522560);

    hipMemsetAsync(g, 0, (size_t)M_DIM * N_DIM * 4, stream);

    const int ntot4 = NX4 + 2 * NW4;
    split_all_kernel<<<(ntot4 + 255) / 256, 256, 0, stream>>>(x, wss, wsc, xh, xl, whi, wlo);

    gemm_split_kernel<<<600 * KSPLIT, 256, 0, stream>>>(xh, xl, whi, wlo, g);

    conv_energy_kernel<<<(B_SZ * T_LEN * NFILT) / 256, 256, 0, stream>>>(g, wts, wtc, out);
}